// Round 1
// baseline (219.056 us; speedup 1.0000x reference)
//
#include <hip/hip_runtime.h>

#define LOG2E 1.4426950408889634f
#define LN2 0.6931471805599453f
#define HALF_LOG_2PI 0.9189385332046727f
#define NEG_INF (-__builtin_inff())

constexpr int Bb = 2, Nn = 256, Ee = 768, Hh = 12, Dd = 64;
constexpr int BN = Bb * Nn;   // 512
constexpr long QC_OFF  = 0;
constexpr long KT_OFF  = 393216;          // keysT [768][512]
constexpr long VC_OFF  = 786432;
constexpr long KM_OFF  = 1179648;         // km [512][768]
constexpr long EN_OFF  = 1572864;         // energy [24][256][256]
constexpr long OA_OFF  = 3145728;         // out_attn [512][768]

// ---------------- generic fp32 tiled GEMM -----------------
// C[row][col] = sum_k A[row][k] * B[k][col]  (BT: B stored as Bphys[col][k])
// 64x64 tile, KT=16, 256 threads, 4x4 micro-tile.
// EPI==0: C (+bias). EPI==1: scatter qkv columns into q/kT/v.
template<bool BT, int EPI>
__global__ __launch_bounds__(256)
void gemm_k(const float* __restrict__ A, int lda, long sAb, long sAh,
            const float* __restrict__ Bm, int ldb, long sBb, long sBh,
            float* __restrict__ C, int ldc, long sCb, long sCh,
            const float* __restrict__ bias, int K, int Hdiv,
            float* __restrict__ eq, float* __restrict__ ek, float* __restrict__ ev)
{
    __shared__ float As[16][68];
    __shared__ float Bs[16][68];
    const int tid = threadIdx.x;
    const int tx = tid & 15, ty = tid >> 4;
    const int m0 = blockIdx.x * 64, n0 = blockIdx.y * 64;
    const int zb = blockIdx.z / Hdiv, zh = blockIdx.z - zb * Hdiv;
    A  += zb * sAb + zh * sAh;
    Bm += zb * sBb + zh * sBh;
    C  += zb * sCb + zh * sCh;
    const int lr = tid >> 2, lc = (tid & 3) * 4;   // 64x16 transposed-store loads
    const int br = tid >> 4, bc = (tid & 15) * 4;  // 16x64 direct loads
    float acc[4][4] = {};
    for (int k0 = 0; k0 < K; k0 += 16) {
        float4 av = *(const float4*)&A[(long)(m0 + lr) * lda + (k0 + lc)];
        float4 bv;
        if (BT) bv = *(const float4*)&Bm[(long)(n0 + lr) * ldb + (k0 + lc)];
        else    bv = *(const float4*)&Bm[(long)(k0 + br) * ldb + (n0 + bc)];
        __syncthreads();
        As[lc + 0][lr] = av.x; As[lc + 1][lr] = av.y;
        As[lc + 2][lr] = av.z; As[lc + 3][lr] = av.w;
        if (BT) {
            Bs[lc + 0][lr] = bv.x; Bs[lc + 1][lr] = bv.y;
            Bs[lc + 2][lr] = bv.z; Bs[lc + 3][lr] = bv.w;
        } else {
            *(float4*)&Bs[br][bc] = bv;
        }
        __syncthreads();
        #pragma unroll
        for (int kk = 0; kk < 16; ++kk) {
            float4 af = *(const float4*)&As[kk][ty * 4];
            float4 bf = *(const float4*)&Bs[kk][tx * 4];
            float aa[4] = {af.x, af.y, af.z, af.w};
            float bb[4] = {bf.x, bf.y, bf.z, bf.w};
            #pragma unroll
            for (int im = 0; im < 4; ++im)
                #pragma unroll
                for (int in = 0; in < 4; ++in)
                    acc[im][in] = fmaf(aa[im], bb[in], acc[im][in]);
        }
    }
    #pragma unroll
    for (int im = 0; im < 4; ++im) {
        const int row = m0 + ty * 4 + im;
        if (EPI == 0) {
            float4 v;
            float* vp = &v.x;
            #pragma unroll
            for (int in = 0; in < 4; ++in) {
                float x = acc[im][in];
                if (bias) x += bias[n0 + tx * 4 + in];
                vp[in] = x;
            }
            *(float4*)&C[(long)row * ldc + (n0 + tx * 4)] = v;
        } else {
            #pragma unroll
            for (int in = 0; in < 4; ++in) {
                const int col = n0 + tx * 4 + in;
                const float x = acc[im][in] + bias[col];
                const int i = col / 3, s = col - i * 3;
                if (s == 0)      eq[(long)row * Ee + i] = x;
                else if (s == 1) ek[(long)i * BN + row] = x;
                else             ev[(long)row * Ee + i] = x;
            }
        }
    }
}

// ---------------- Gaussian-mixture logsumexp -----------------
// block = one i (768 blocks), 4 waves. Table coeffs (quadratic in key, base-2
// log space) built in registers; wave handles one (b,n) row per inner iter,
// lanes cover the j-axis (12 j per lane, t2 kept in registers -> 1 exp2/eval).
__global__ __launch_bounds__(256)
void k_mixture(const float* __restrict__ mean, const float* __restrict__ logvar,
               const float* __restrict__ mix, const float* __restrict__ keysT,
               float* __restrict__ km)
{
    const int i = blockIdx.x;
    const int lane = threadIdx.x & 63;
    const int w = threadIdx.x >> 6;

    // log_softmax normalizer of mix_coef (redundant per block, trivial)
    float mx[12];
    float mm = NEG_INF;
    #pragma unroll
    for (int r = 0; r < 12; ++r) {
        mx[r] = mix[lane + 64 * r];
        mm = fmaxf(mm, mx[r]);
    }
    #pragma unroll
    for (int off = 32; off; off >>= 1) mm = fmaxf(mm, __shfl_xor(mm, off, 64));
    float ss = 0.f;
    #pragma unroll
    for (int r = 0; r < 12; ++r) ss += __builtin_amdgcn_exp2f((mx[r] - mm) * LOG2E);
    #pragma unroll
    for (int off = 32; off; off >>= 1) ss += __shfl_xor(ss, off, 64);
    const float lz = mm + LN2 * __builtin_amdgcn_logf(ss);

    // per-(i,j) quadratic coefficients, base-2:
    // t2 = A*k^2 + B*k + C,  A=-0.5*log2e*istd2, B=log2e*mu*istd2,
    // C=log2e*(logmix - 0.5*lv - 0.5*ln(2pi) - 0.5*mu^2*istd2)
    float a[12], b[12], c[12];
    #pragma unroll
    for (int r = 0; r < 12; ++r) {
        const int idx = i * Ee + lane + 64 * r;
        const float lv = logvar[idx], mu = mean[idx];
        const float istd2 = __builtin_amdgcn_exp2f(-lv * LOG2E);
        a[r] = -0.5f * LOG2E * istd2;
        b[r] = LOG2E * mu * istd2;
        c[r] = LOG2E * (mx[r] - lz - 0.5f * lv - HALF_LOG_2PI - 0.5f * mu * mu * istd2);
    }

    for (int ch = w; ch < 8; ch += 4) {
        const float kvec = keysT[(long)i * BN + ch * 64 + lane];
        for (int rr = 0; rr < 64; ++rr) {
            const float kv = __shfl(kvec, rr, 64);
            const float k2 = kv * kv;
            float t[12];
            float m = NEG_INF;
            #pragma unroll
            for (int r = 0; r < 12; ++r) {
                t[r] = fmaf(a[r], k2, fmaf(b[r], kv, c[r]));
                m = fmaxf(m, t[r]);
            }
            #pragma unroll
            for (int off = 32; off; off >>= 1) m = fmaxf(m, __shfl_xor(m, off, 64));
            float s = 0.f;
            #pragma unroll
            for (int r = 0; r < 12; ++r) s += __builtin_amdgcn_exp2f(t[r] - m);
            #pragma unroll
            for (int off = 32; off; off >>= 1) s += __shfl_xor(s, off, 64);
            if (lane == 0)
                km[(long)(ch * 64 + rr) * Ee + i] = LN2 * (m + __builtin_amdgcn_logf(s));
        }
    }
}

// ---------------- row softmax (in-place) with /sqrt(768) folded ------------
__global__ __launch_bounds__(256)
void k_softmax(float* __restrict__ e)
{
    const int row = blockIdx.x * 4 + (threadIdx.x >> 6);
    const int lane = threadIdx.x & 63;
    float4* p = (float4*)(e + (long)row * 256);
    float4 v = p[lane];
    float m = fmaxf(fmaxf(v.x, v.y), fmaxf(v.z, v.w));
    #pragma unroll
    for (int off = 32; off; off >>= 1) m = fmaxf(m, __shfl_xor(m, off, 64));
    v.x = __builtin_amdgcn_exp2f((v.x - m) * LOG2E);
    v.y = __builtin_amdgcn_exp2f((v.y - m) * LOG2E);
    v.z = __builtin_amdgcn_exp2f((v.z - m) * LOG2E);
    v.w = __builtin_amdgcn_exp2f((v.w - m) * LOG2E);
    float s = v.x + v.y + v.z + v.w;
    #pragma unroll
    for (int off = 32; off; off >>= 1) s += __shfl_xor(s, off, 64);
    const float sc = 1.0f / (s * 27.712812921102035f);  // * sqrt(768)
    v.x *= sc; v.y *= sc; v.z *= sc; v.w *= sc;
    p[lane] = v;
}

extern "C" void kernel_launch(void* const* d_in, const int* in_sizes, int n_in,
                              void* d_out, int out_size, void* d_ws, size_t ws_size,
                              hipStream_t stream)
{
    (void)in_sizes; (void)n_in; (void)out_size; (void)ws_size;
    const float* x      = (const float*)d_in[0];
    const float* Wqkv   = (const float*)d_in[1];
    const float* bqkv   = (const float*)d_in[2];
    const float* Wproj  = (const float*)d_in[3];
    const float* bproj  = (const float*)d_in[4];
    const float* mean   = (const float*)d_in[5];
    const float* logvar = (const float*)d_in[6];
    const float* mixc   = (const float*)d_in[7];
    float* out = (float*)d_out;
    float* ws = (float*)d_ws;
    float* qc     = ws + QC_OFF;
    float* keysT  = ws + KT_OFF;
    float* vc     = ws + VC_OFF;
    float* km     = ws + KM_OFF;
    float* energy = ws + EN_OFF;
    float* oat    = ws + OA_OFF;

    // 1) qkv = x @ Wqkv + bqkv, scattered to q/kT/v
    gemm_k<false,1><<<dim3(8,36,1),256,0,stream>>>(
        x,768,0,0, Wqkv,2304,0,0, qc,0,0,0, bqkv, 768, 1, qc,keysT,vc);
    // 2) key_mix
    k_mixture<<<768,256,0,stream>>>(mean, logvar, mixc, keysT, km);
    // 3) energy[b,h,q,k] = sum_d q * km   (BT gemm, batched over b,h)
    gemm_k<true,0><<<dim3(4,4,24),256,0,stream>>>(
        qc,768,196608,64, km,768,196608,64, energy,256,786432,65536,
        nullptr, 64, 12, nullptr,nullptr,nullptr);
    // 4) att = softmax(energy)/sqrt(768), in place
    k_softmax<<<1536,256,0,stream>>>(energy);
    // 5) out_attn = att @ v
    gemm_k<false,0><<<dim3(4,1,24),256,0,stream>>>(
        energy,256,786432,65536, vc,768,196608,64, oat,768,196608,64,
        nullptr, 256, 12, nullptr,nullptr,nullptr);
    // 6) out = out_attn @ Wproj + bproj
    gemm_k<false,0><<<dim3(8,12,1),256,0,stream>>>(
        oat,768,0,0, Wproj,768,0,0, out,768,0,0, bproj, 768, 1,
        nullptr,nullptr,nullptr);
}

// Round 2
// 140.463 us; speedup vs baseline: 1.5595x; 1.5595x over previous
//
#include <hip/hip_runtime.h>

#define LOG2E 1.4426950408889634f
#define LN2 0.6931471805599453f
#define NEG_INF (-__builtin_inff())

constexpr int Bb = 2, Nn = 256, Ee = 768, Hh = 12, Dd = 64;
constexpr int BN = Bb * Nn;   // 512
constexpr long QC_OFF  = 0;
constexpr long KT_OFF  = 393216;          // keysT [768][512]
constexpr long VC_OFF  = 786432;
constexpr long KM_OFF  = 1179648;         // kmT [768][512]
constexpr long EN_OFF  = 1572864;         // energy [24][256][256]
constexpr long OA_OFF  = 3145728;         // out_attn [512][768]

// ---------------- fp32 tiled GEMM, 32x64 tile, KT=16, 256 thr, 2x4 micro ---
// C[row][col] = sum_k A[row][k] * B[k][col]
// EPI==0: C (+bias). EPI==1: scatter qkv columns into q/kT/v.
template<int EPI>
__global__ __launch_bounds__(256)
void gemm_k(const float* __restrict__ A, int lda, long sAb, long sAh,
            const float* __restrict__ Bm, int ldb, long sBb, long sBh,
            float* __restrict__ C, int ldc, long sCb, long sCh,
            const float* __restrict__ bias, int K, int Hdiv,
            float* __restrict__ eq, float* __restrict__ ek, float* __restrict__ ev)
{
    __shared__ float As[16][34];   // [k][m], padded stride 34 (8B-aligned float2)
    __shared__ float Bs[16][68];   // [k][n]
    const int tid = threadIdx.x;
    const int tx = tid & 15, ty = tid >> 4;      // tx: n/4, ty: m/2
    const int m0 = blockIdx.x * 32, n0 = blockIdx.y * 64;
    const int zb = blockIdx.z / Hdiv, zh = blockIdx.z - zb * Hdiv;
    A  += zb * sAb + zh * sAh;
    Bm += zb * sBb + zh * sBh;
    C  += zb * sCb + zh * sCh;
    const int lr = tid >> 3, lc2 = (tid & 7) * 2;   // A: 32 rows x 16 k
    const int br = tid >> 4, bc = (tid & 15) * 4;   // B: 16 k x 64 n
    float acc[2][4] = {};
    // prefetch first K-tile into registers
    float2 av = *(const float2*)&A[(long)(m0 + lr) * lda + lc2];
    float4 bv = *(const float4*)&Bm[(long)br * ldb + (n0 + bc)];
    for (int k0 = 0; k0 < K; k0 += 16) {
        __syncthreads();
        As[lc2 + 0][lr] = av.x;
        As[lc2 + 1][lr] = av.y;
        *(float4*)&Bs[br][bc] = bv;
        __syncthreads();
        if (k0 + 16 < K) {   // issue next-tile loads; latency hides under compute
            av = *(const float2*)&A[(long)(m0 + lr) * lda + (k0 + 16 + lc2)];
            bv = *(const float4*)&Bm[(long)(k0 + 16 + br) * ldb + (n0 + bc)];
        }
        #pragma unroll
        for (int kk = 0; kk < 16; ++kk) {
            float2 a = *(const float2*)&As[kk][ty * 2];
            float4 b = *(const float4*)&Bs[kk][tx * 4];
            acc[0][0] = fmaf(a.x, b.x, acc[0][0]);
            acc[0][1] = fmaf(a.x, b.y, acc[0][1]);
            acc[0][2] = fmaf(a.x, b.z, acc[0][2]);
            acc[0][3] = fmaf(a.x, b.w, acc[0][3]);
            acc[1][0] = fmaf(a.y, b.x, acc[1][0]);
            acc[1][1] = fmaf(a.y, b.y, acc[1][1]);
            acc[1][2] = fmaf(a.y, b.z, acc[1][2]);
            acc[1][3] = fmaf(a.y, b.w, acc[1][3]);
        }
    }
    #pragma unroll
    for (int im = 0; im < 2; ++im) {
        const int row = m0 + ty * 2 + im;
        if (EPI == 0) {
            float4 v;
            float* vp = &v.x;
            #pragma unroll
            for (int in = 0; in < 4; ++in) {
                float x = acc[im][in];
                if (bias) x += bias[n0 + tx * 4 + in];
                vp[in] = x;
            }
            *(float4*)&C[(long)row * ldc + (n0 + tx * 4)] = v;
        } else {
            #pragma unroll
            for (int in = 0; in < 4; ++in) {
                const int col = n0 + tx * 4 + in;
                const float x = acc[im][in] + bias[col];
                const int i = col / 3, s = col - i * 3;
                if (s == 0)      eq[(long)row * Ee + i] = x;
                else if (s == 1) ek[(long)i * BN + row] = x;
                else             ev[(long)row * Ee + i] = x;
            }
        }
    }
}

// ---------------- Gaussian-mixture logsumexp (v2) -----------------
// block = (i, half of rows); lane owns one (b,n) row; j-loop over 768
// components with wave-uniform coefficients broadcast from LDS.
// Constants -lz (mix log-softmax normalizer) and -0.5*log(2pi) are dropped:
// they shift key_mix uniformly -> energy shifts by const*sum_d(q) per q-row
// -> softmax-invariant. No max pass: t <= ~8 in base-2, overflow impossible.
__global__ __launch_bounds__(256)
void k_mixture(const float* __restrict__ mean, const float* __restrict__ logvar,
               const float* __restrict__ mix, const float* __restrict__ keysT,
               float* __restrict__ kmT)
{
    __shared__ float aS[768], bS[768], cS[768];
    const int i = blockIdx.x >> 1;
    const int half = blockIdx.x & 1;
    const int tid = threadIdx.x;

    #pragma unroll
    for (int r = 0; r < 3; ++r) {
        const int j = tid + r * 256;
        const float lv = logvar[i * Ee + j];
        const float mu = mean[i * Ee + j];
        const float istd2 = __builtin_amdgcn_exp2f(-lv * LOG2E);
        aS[j] = -0.5f * LOG2E * istd2;
        bS[j] = LOG2E * mu * istd2;
        cS[j] = fmaf(-0.5f * LOG2E * mu * mu, istd2, LOG2E * (mix[j] - 0.5f * lv));
    }
    __syncthreads();

    const int row = half * 256 + tid;
    const float kv = keysT[(long)i * BN + row];
    const float k2 = kv * kv;
    const float4* a4 = (const float4*)aS;
    const float4* b4 = (const float4*)bS;
    const float4* c4 = (const float4*)cS;
    float s = 0.f;
    #pragma unroll 2
    for (int j4 = 0; j4 < 192; ++j4) {
        const float4 a = a4[j4], b = b4[j4], c = c4[j4];
        s += __builtin_amdgcn_exp2f(fmaf(a.x, k2, fmaf(b.x, kv, c.x)));
        s += __builtin_amdgcn_exp2f(fmaf(a.y, k2, fmaf(b.y, kv, c.y)));
        s += __builtin_amdgcn_exp2f(fmaf(a.z, k2, fmaf(b.z, kv, c.z)));
        s += __builtin_amdgcn_exp2f(fmaf(a.w, k2, fmaf(b.w, kv, c.w)));
    }
    kmT[(long)i * BN + row] = LN2 * __builtin_amdgcn_logf(s);
}

// ---------------- row softmax (in-place) with /sqrt(768) folded ------------
__global__ __launch_bounds__(256)
void k_softmax(float* __restrict__ e)
{
    const int row = blockIdx.x * 4 + (threadIdx.x >> 6);
    const int lane = threadIdx.x & 63;
    float4* p = (float4*)(e + (long)row * 256);
    float4 v = p[lane];
    float m = fmaxf(fmaxf(v.x, v.y), fmaxf(v.z, v.w));
    #pragma unroll
    for (int off = 32; off; off >>= 1) m = fmaxf(m, __shfl_xor(m, off, 64));
    v.x = __builtin_amdgcn_exp2f((v.x - m) * LOG2E);
    v.y = __builtin_amdgcn_exp2f((v.y - m) * LOG2E);
    v.z = __builtin_amdgcn_exp2f((v.z - m) * LOG2E);
    v.w = __builtin_amdgcn_exp2f((v.w - m) * LOG2E);
    float s = v.x + v.y + v.z + v.w;
    #pragma unroll
    for (int off = 32; off; off >>= 1) s += __shfl_xor(s, off, 64);
    const float sc = 1.0f / (s * 27.712812921102035f);  // * sqrt(768)
    v.x *= sc; v.y *= sc; v.z *= sc; v.w *= sc;
    p[lane] = v;
}

extern "C" void kernel_launch(void* const* d_in, const int* in_sizes, int n_in,
                              void* d_out, int out_size, void* d_ws, size_t ws_size,
                              hipStream_t stream)
{
    (void)in_sizes; (void)n_in; (void)out_size; (void)ws_size;
    const float* x      = (const float*)d_in[0];
    const float* Wqkv   = (const float*)d_in[1];
    const float* bqkv   = (const float*)d_in[2];
    const float* Wproj  = (const float*)d_in[3];
    const float* bproj  = (const float*)d_in[4];
    const float* mean   = (const float*)d_in[5];
    const float* logvar = (const float*)d_in[6];
    const float* mixc   = (const float*)d_in[7];
    float* out = (float*)d_out;
    float* ws = (float*)d_ws;
    float* qc     = ws + QC_OFF;
    float* keysT  = ws + KT_OFF;
    float* vc     = ws + VC_OFF;
    float* kmT    = ws + KM_OFF;
    float* energy = ws + EN_OFF;
    float* oat    = ws + OA_OFF;

    // 1) qkv = x @ Wqkv + bqkv, scattered to q/keysT/v
    gemm_k<1><<<dim3(16,36,1),256,0,stream>>>(
        x,768,0,0, Wqkv,2304,0,0, qc,0,0,0, bqkv, 768, 1, qc,keysT,vc);
    // 2) key_mix (transposed output kmT[i][row])
    k_mixture<<<1536,256,0,stream>>>(mean, logvar, mixc, keysT, kmT);
    // 3) energy[b,h,q,k] = sum_d q[.,d] * kmT[d][k]   (B non-transposed, ldb=512)
    gemm_k<0><<<dim3(8,4,24),256,0,stream>>>(
        qc,768,196608,64, kmT,512,256,32768, energy,256,786432,65536,
        nullptr, 64, 12, nullptr,nullptr,nullptr);
    // 4) att = softmax(energy)/sqrt(768), in place
    k_softmax<<<1536,256,0,stream>>>(energy);
    // 5) out_attn = att @ v
    gemm_k<0><<<dim3(8,1,24),256,0,stream>>>(
        energy,256,786432,65536, vc,768,196608,64, oat,768,196608,64,
        nullptr, 256, 12, nullptr,nullptr,nullptr);
    // 6) out = out_attn @ Wproj + bproj
    gemm_k<0><<<dim3(16,12,1),256,0,stream>>>(
        oat,768,0,0, Wproj,768,0,0, out,768,0,0, bproj, 768, 1,
        nullptr,nullptr,nullptr);
}

// Round 3
// 140.189 us; speedup vs baseline: 1.5626x; 1.0020x over previous
//
#include <hip/hip_runtime.h>

#define LOG2E 1.4426950408889634f
#define LN2 0.6931471805599453f

constexpr int Bb = 2, Nn = 256, Ee = 768, Hh = 12, Dd = 64;
constexpr int BN = Bb * Nn;   // 512
constexpr long QC_OFF  = 0;
constexpr long KT_OFF  = 393216;          // keysT [768][512]
constexpr long VC_OFF  = 786432;
constexpr long KM_OFF  = 1179648;         // kmT [768][512]
constexpr long EN_OFF  = 1572864;         // energy [24][256][256]
constexpr long OA_OFF  = 3145728;         // out_attn [512][768]

// ---------------- fp32 tiled GEMM, 32x64 tile, KT=16, 128 thr, 4x4 micro ---
// C[row][col] = sum_k A[row][k] * B[k][col]
// EPI==0: C (+bias). EPI==1: scatter qkv columns into q/kT/v.
// 128 threads: tx=tid&15 (n/4), ty=tid>>4 (m/4, 0..7). 16 FMA per 2 b128
// LDS reads -> FMA-bound inner loop; reg double-buffer hides global latency.
template<int EPI>
__global__ __launch_bounds__(128)
void gemm_k(const float* __restrict__ A, int lda, long sAb, long sAh,
            const float* __restrict__ Bm, int ldb, long sBb, long sBh,
            float* __restrict__ C, int ldc, long sCb, long sCh,
            const float* __restrict__ bias, int K, int Hdiv,
            float* __restrict__ eq, float* __restrict__ ek, float* __restrict__ ev)
{
    __shared__ __align__(16) float As[16][36];   // [k][m], stride 36: 16B-aligned rows, 2-way banks
    __shared__ __align__(16) float Bs[16][68];   // [k][n]
    const int tid = threadIdx.x;
    const int tx = tid & 15, ty = tid >> 4;
    const int m0 = blockIdx.x * 32, n0 = blockIdx.y * 64;
    const int zb = blockIdx.z / Hdiv, zh = blockIdx.z - zb * Hdiv;
    A  += zb * sAb + zh * sAh;
    Bm += zb * sBb + zh * sBh;
    C  += zb * sCb + zh * sCh;
    const int ar = tid >> 2, ac = (tid & 3) * 4;    // A: 32 rows x 16 k, 1 float4/thr
    const int br = tid >> 4, bc = (tid & 15) * 4;   // B: 16 k x 64 n, 2 float4/thr
    float acc[4][4] = {};
    // prefetch first K-tile into registers
    float4 av  = *(const float4*)&A[(long)(m0 + ar) * lda + ac];
    float4 bv0 = *(const float4*)&Bm[(long)(br + 0) * ldb + (n0 + bc)];
    float4 bv1 = *(const float4*)&Bm[(long)(br + 8) * ldb + (n0 + bc)];
    for (int k0 = 0; k0 < K; k0 += 16) {
        __syncthreads();
        As[ac + 0][ar] = av.x; As[ac + 1][ar] = av.y;
        As[ac + 2][ar] = av.z; As[ac + 3][ar] = av.w;
        *(float4*)&Bs[br + 0][bc] = bv0;
        *(float4*)&Bs[br + 8][bc] = bv1;
        __syncthreads();
        if (k0 + 16 < K) {   // next-tile loads overlap compute below
            av  = *(const float4*)&A[(long)(m0 + ar) * lda + (k0 + 16 + ac)];
            bv0 = *(const float4*)&Bm[(long)(k0 + 16 + br + 0) * ldb + (n0 + bc)];
            bv1 = *(const float4*)&Bm[(long)(k0 + 16 + br + 8) * ldb + (n0 + bc)];
        }
        #pragma unroll
        for (int kk = 0; kk < 16; ++kk) {
            const float4 a = *(const float4*)&As[kk][ty * 4];
            const float4 b = *(const float4*)&Bs[kk][tx * 4];
            const float aa[4] = {a.x, a.y, a.z, a.w};
            const float bb[4] = {b.x, b.y, b.z, b.w};
            #pragma unroll
            for (int im = 0; im < 4; ++im)
                #pragma unroll
                for (int in = 0; in < 4; ++in)
                    acc[im][in] = fmaf(aa[im], bb[in], acc[im][in]);
        }
    }
    #pragma unroll
    for (int im = 0; im < 4; ++im) {
        const int row = m0 + ty * 4 + im;
        if (EPI == 0) {
            float4 v;
            float* vp = &v.x;
            #pragma unroll
            for (int in = 0; in < 4; ++in) {
                float x = acc[im][in];
                if (bias) x += bias[n0 + tx * 4 + in];
                vp[in] = x;
            }
            *(float4*)&C[(long)row * ldc + (n0 + tx * 4)] = v;
        } else {
            #pragma unroll
            for (int in = 0; in < 4; ++in) {
                const int col = n0 + tx * 4 + in;
                const float x = acc[im][in] + bias[col];
                const int i = col / 3, s = col - i * 3;
                if (s == 0)      eq[(long)row * Ee + i] = x;
                else if (s == 1) ek[(long)i * BN + row] = x;
                else             ev[(long)row * Ee + i] = x;
            }
        }
    }
}

// ---------------- Gaussian-mixture logsumexp -----------------
// block = (i, half of rows); lane owns one (b,n) row; j-loop over 768
// components with wave-uniform coefficients broadcast from LDS.
// Constants -lz (mix log-softmax normalizer) and -0.5*log(2pi) dropped:
// uniform shift of key_mix -> softmax-invariant. No max pass needed
// (t <= ~8 in base-2 log space; overflow impossible, all-underflow impossible).
__global__ __launch_bounds__(256)
void k_mixture(const float* __restrict__ mean, const float* __restrict__ logvar,
               const float* __restrict__ mix, const float* __restrict__ keysT,
               float* __restrict__ kmT)
{
    __shared__ float aS[768], bS[768], cS[768];
    const int i = blockIdx.x >> 1;
    const int half = blockIdx.x & 1;
    const int tid = threadIdx.x;

    #pragma unroll
    for (int r = 0; r < 3; ++r) {
        const int j = tid + r * 256;
        const float lv = logvar[i * Ee + j];
        const float mu = mean[i * Ee + j];
        const float istd2 = __builtin_amdgcn_exp2f(-lv * LOG2E);
        aS[j] = -0.5f * LOG2E * istd2;
        bS[j] = LOG2E * mu * istd2;
        cS[j] = fmaf(-0.5f * LOG2E * mu * mu, istd2, LOG2E * (mix[j] - 0.5f * lv));
    }
    __syncthreads();

    const int row = half * 256 + tid;
    const float kv = keysT[(long)i * BN + row];
    const float k2 = kv * kv;
    const float4* a4 = (const float4*)aS;
    const float4* b4 = (const float4*)bS;
    const float4* c4 = (const float4*)cS;
    float s = 0.f;
    #pragma unroll 2
    for (int j4 = 0; j4 < 192; ++j4) {
        const float4 a = a4[j4], b = b4[j4], c = c4[j4];
        s += __builtin_amdgcn_exp2f(fmaf(a.x, k2, fmaf(b.x, kv, c.x)));
        s += __builtin_amdgcn_exp2f(fmaf(a.y, k2, fmaf(b.y, kv, c.y)));
        s += __builtin_amdgcn_exp2f(fmaf(a.z, k2, fmaf(b.z, kv, c.z)));
        s += __builtin_amdgcn_exp2f(fmaf(a.w, k2, fmaf(b.w, kv, c.w)));
    }
    kmT[(long)i * BN + row] = LN2 * __builtin_amdgcn_logf(s);
}

// ---------------- row softmax (in-place) with /sqrt(768) folded ------------
__global__ __launch_bounds__(256)
void k_softmax(float* __restrict__ e)
{
    const int row = blockIdx.x * 4 + (threadIdx.x >> 6);
    const int lane = threadIdx.x & 63;
    float4* p = (float4*)(e + (long)row * 256);
    float4 v = p[lane];
    float m = fmaxf(fmaxf(v.x, v.y), fmaxf(v.z, v.w));
    #pragma unroll
    for (int off = 32; off; off >>= 1) m = fmaxf(m, __shfl_xor(m, off, 64));
    v.x = __builtin_amdgcn_exp2f((v.x - m) * LOG2E);
    v.y = __builtin_amdgcn_exp2f((v.y - m) * LOG2E);
    v.z = __builtin_amdgcn_exp2f((v.z - m) * LOG2E);
    v.w = __builtin_amdgcn_exp2f((v.w - m) * LOG2E);
    float s = v.x + v.y + v.z + v.w;
    #pragma unroll
    for (int off = 32; off; off >>= 1) s += __shfl_xor(s, off, 64);
    const float sc = 1.0f / (s * 27.712812921102035f);  // * sqrt(768)
    v.x *= sc; v.y *= sc; v.z *= sc; v.w *= sc;
    p[lane] = v;
}

extern "C" void kernel_launch(void* const* d_in, const int* in_sizes, int n_in,
                              void* d_out, int out_size, void* d_ws, size_t ws_size,
                              hipStream_t stream)
{
    (void)in_sizes; (void)n_in; (void)out_size; (void)ws_size;
    const float* x      = (const float*)d_in[0];
    const float* Wqkv   = (const float*)d_in[1];
    const float* bqkv   = (const float*)d_in[2];
    const float* Wproj  = (const float*)d_in[3];
    const float* bproj  = (const float*)d_in[4];
    const float* mean   = (const float*)d_in[5];
    const float* logvar = (const float*)d_in[6];
    const float* mixc   = (const float*)d_in[7];
    float* out = (float*)d_out;
    float* ws = (float*)d_ws;
    float* qc     = ws + QC_OFF;
    float* keysT  = ws + KT_OFF;
    float* vc     = ws + VC_OFF;
    float* kmT    = ws + KM_OFF;
    float* energy = ws + EN_OFF;
    float* oat    = ws + OA_OFF;

    // 1) qkv = x @ Wqkv + bqkv, scattered to q/keysT/v
    gemm_k<1><<<dim3(16,36,1),128,0,stream>>>(
        x,768,0,0, Wqkv,2304,0,0, qc,0,0,0, bqkv, 768, 1, qc,keysT,vc);
    // 2) key_mix (transposed output kmT[i][row])
    k_mixture<<<1536,256,0,stream>>>(mean, logvar, mixc, keysT, kmT);
    // 3) energy[b,h,q,k] = sum_d q[.,d] * kmT[d][k]
    gemm_k<0><<<dim3(8,4,24),128,0,stream>>>(
        qc,768,196608,64, kmT,512,256,32768, energy,256,786432,65536,
        nullptr, 64, 12, nullptr,nullptr,nullptr);
    // 4) att = softmax(energy)/sqrt(768), in place
    k_softmax<<<1536,256,0,stream>>>(energy);
    // 5) out_attn = att @ v
    gemm_k<0><<<dim3(8,1,24),128,0,stream>>>(
        energy,256,786432,65536, vc,768,196608,64, oat,768,196608,64,
        nullptr, 256, 12, nullptr,nullptr,nullptr);
    // 6) out = out_attn @ Wproj + bproj
    gemm_k<0><<<dim3(16,12,1),128,0,stream>>>(
        oat,768,0,0, Wproj,768,0,0, out,768,0,0, bproj, 768, 1,
        nullptr,nullptr,nullptr);
}

// Round 4
// 139.096 us; speedup vs baseline: 1.5749x; 1.0079x over previous
//
#include <hip/hip_runtime.h>

#define LOG2E 1.4426950408889634f
#define LN2 0.6931471805599453f

constexpr int Ee = 768;
constexpr int BN = 512;
// ws layout (floats). P (qkv partials) overlaps kmT/energy/oat: P is dead
// before any of those are written. High-water = 3538944 floats = 14.2 MB.
constexpr long QC_OFF = 0;              // q       [512][768]
constexpr long KT_OFF = 393216;         // keysT   [768][512]
constexpr long VC_OFF = 786432;         // v       [512][768]
constexpr long P_OFF  = 1179648;        // qkv partials [2][512][2304]
constexpr long PSTRIDE = 1179648;
constexpr long KM_OFF = 1179648;        // kmT     [768][512]   (after reduce)
constexpr long EN_OFF = 1572864;        // energy  [24][256][256]
constexpr long OA_OFF = 3145728;        // out_attn[512][768]

// ---------------- fp32 tiled GEMM, BMx64 tile, KT=16, 128 threads ----------
// C[row][col] = sum_k A[row][k]*B[k][col]; optional K-split (KS parts, each
// this kernel's K deep, partial written at C + kp*sCp; caller reduces).
// BM=32: 4x4 micro. BM=16: 2x4 micro (for small-M / more blocks).
template<int BM>
__global__ __launch_bounds__(128)
void gemm_k(const float* __restrict__ A, int lda, long sAb, long sAh,
            const float* __restrict__ Bm, int ldb, long sBb, long sBh,
            float* __restrict__ C, int ldc, long sCb, long sCh, long sCp,
            const float* __restrict__ bias, int K, int Hdiv, int KS)
{
    __shared__ __align__(16) float As[16][BM + 4];
    __shared__ __align__(16) float Bs[16][68];
    const int tid = threadIdx.x;
    const int tx = tid & 15, ty = tid >> 4;
    constexpr int MR = BM / 8;
    const int m0 = blockIdx.x * BM, n0 = blockIdx.y * 64;
    const int kp = blockIdx.z % KS;
    const int zz = blockIdx.z / KS;
    const int zb = zz / Hdiv, zh = zz - zb * Hdiv;
    A  += zb * sAb + zh * sAh + (long)kp * K;
    Bm += zb * sBb + zh * sBh + (long)kp * K * ldb;
    C  += zb * sCb + zh * sCh + (long)kp * sCp;
    const int br = tid >> 4, bc = (tid & 15) * 4;
    const int ar = (BM == 32) ? (tid >> 2) : (tid >> 3);
    const int ac = (BM == 32) ? ((tid & 3) * 4) : ((tid & 7) * 2);
    float acc[MR][4] = {};

    float4 av; float2 av2;
    if constexpr (BM == 32) av  = *(const float4*)&A[(long)(m0 + ar) * lda + ac];
    else                    av2 = *(const float2*)&A[(long)(m0 + ar) * lda + ac];
    float4 bv0 = *(const float4*)&Bm[(long)(br + 0) * ldb + (n0 + bc)];
    float4 bv1 = *(const float4*)&Bm[(long)(br + 8) * ldb + (n0 + bc)];

    for (int k0 = 0; k0 < K; k0 += 16) {
        __syncthreads();
        if constexpr (BM == 32) {
            As[ac + 0][ar] = av.x; As[ac + 1][ar] = av.y;
            As[ac + 2][ar] = av.z; As[ac + 3][ar] = av.w;
        } else {
            As[ac + 0][ar] = av2.x; As[ac + 1][ar] = av2.y;
        }
        *(float4*)&Bs[br + 0][bc] = bv0;
        *(float4*)&Bs[br + 8][bc] = bv1;
        __syncthreads();
        if (k0 + 16 < K) {   // next-tile loads overlap compute below
            if constexpr (BM == 32) av  = *(const float4*)&A[(long)(m0 + ar) * lda + (k0 + 16 + ac)];
            else                    av2 = *(const float2*)&A[(long)(m0 + ar) * lda + (k0 + 16 + ac)];
            bv0 = *(const float4*)&Bm[(long)(k0 + 16 + br + 0) * ldb + (n0 + bc)];
            bv1 = *(const float4*)&Bm[(long)(k0 + 16 + br + 8) * ldb + (n0 + bc)];
        }
        #pragma unroll
        for (int kk = 0; kk < 16; ++kk) {
            float aa[MR];
            if constexpr (BM == 32) {
                const float4 a = *(const float4*)&As[kk][ty * 4];
                aa[0] = a.x; aa[1] = a.y; aa[2] = a.z; aa[3] = a.w;
            } else {
                const float2 a = *(const float2*)&As[kk][ty * 2];
                aa[0] = a.x; aa[1] = a.y;
            }
            const float4 b = *(const float4*)&Bs[kk][tx * 4];
            const float bb[4] = {b.x, b.y, b.z, b.w};
            #pragma unroll
            for (int im = 0; im < MR; ++im)
                #pragma unroll
                for (int in = 0; in < 4; ++in)
                    acc[im][in] = fmaf(aa[im], bb[in], acc[im][in]);
        }
    }
    #pragma unroll
    for (int im = 0; im < MR; ++im) {
        const int row = m0 + ty * MR + im;
        float4 v;
        float* vp = &v.x;
        #pragma unroll
        for (int in = 0; in < 4; ++in) {
            float x = acc[im][in];
            if (bias) x += bias[n0 + tx * 4 + in];
            vp[in] = x;
        }
        *(float4*)&C[(long)row * ldc + (n0 + tx * 4)] = v;
    }
}

// ------------- qkv K-split reduce + bias + scatter to q/keysT/v ------------
__global__ __launch_bounds__(256)
void k_qkvreduce(const float* __restrict__ P, const float* __restrict__ bias,
                 float* __restrict__ q, float* __restrict__ kT,
                 float* __restrict__ v)
{
    const int t = blockIdx.x * 256 + threadIdx.x;      // float4 id, 294912 total
    const int row = t / 576;
    const int c4 = (t - row * 576) * 4;
    const float4 p0 = *(const float4*)&P[(long)row * 2304 + c4];
    const float4 p1 = *(const float4*)&P[PSTRIDE + (long)row * 2304 + c4];
    const float4 bb = *(const float4*)&bias[c4];
    const float r[4] = {p0.x + p1.x + bb.x, p0.y + p1.y + bb.y,
                        p0.z + p1.z + bb.z, p0.w + p1.w + bb.w};
    #pragma unroll
    for (int e = 0; e < 4; ++e) {
        const int col = c4 + e;
        const int i = col / 3, s = col - i * 3;
        if (s == 0)      q [(long)row * Ee + i]  = r[e];
        else if (s == 1) kT[(long)i * BN + row]  = r[e];
        else             v [(long)row * Ee + i]  = r[e];
    }
}

// ---------------- Gaussian-mixture logsumexp -----------------
// lane owns one (b,n) row; j-loop over 768 components, wave-uniform coeff
// broadcast from LDS. Mix log-softmax normalizer + 0.5*log(2pi) dropped
// (uniform shift -> softmax-invariant). No max pass (t <= ~8 base-2).
__global__ __launch_bounds__(256)
void k_mixture(const float* __restrict__ mean, const float* __restrict__ logvar,
               const float* __restrict__ mix, const float* __restrict__ keysT,
               float* __restrict__ kmT)
{
    __shared__ float aS[768], bS[768], cS[768];
    const int i = blockIdx.x >> 1;
    const int half = blockIdx.x & 1;
    const int tid = threadIdx.x;

    #pragma unroll
    for (int r = 0; r < 3; ++r) {
        const int j = tid + r * 256;
        const float lv = logvar[i * Ee + j];
        const float mu = mean[i * Ee + j];
        const float istd2 = __builtin_amdgcn_exp2f(-lv * LOG2E);
        aS[j] = -0.5f * LOG2E * istd2;
        bS[j] = LOG2E * mu * istd2;
        cS[j] = fmaf(-0.5f * LOG2E * mu * mu, istd2, LOG2E * (mix[j] - 0.5f * lv));
    }
    __syncthreads();

    const int row = half * 256 + tid;
    const float kv = keysT[(long)i * BN + row];
    const float k2 = kv * kv;
    const float4* a4 = (const float4*)aS;
    const float4* b4 = (const float4*)bS;
    const float4* c4 = (const float4*)cS;
    float s = 0.f;
    #pragma unroll 2
    for (int j4 = 0; j4 < 192; ++j4) {
        const float4 a = a4[j4], b = b4[j4], c = c4[j4];
        s += __builtin_amdgcn_exp2f(fmaf(a.x, k2, fmaf(b.x, kv, c.x)));
        s += __builtin_amdgcn_exp2f(fmaf(a.y, k2, fmaf(b.y, kv, c.y)));
        s += __builtin_amdgcn_exp2f(fmaf(a.z, k2, fmaf(b.z, kv, c.z)));
        s += __builtin_amdgcn_exp2f(fmaf(a.w, k2, fmaf(b.w, kv, c.w)));
    }
    kmT[(long)i * BN + row] = LN2 * __builtin_amdgcn_logf(s);
}

// ---------------- row softmax (in-place) with /sqrt(768) folded ------------
__global__ __launch_bounds__(256)
void k_softmax(float* __restrict__ e)
{
    const int row = blockIdx.x * 4 + (threadIdx.x >> 6);
    const int lane = threadIdx.x & 63;
    float4* p = (float4*)(e + (long)row * 256);
    float4 v = p[lane];
    float m = fmaxf(fmaxf(v.x, v.y), fmaxf(v.z, v.w));
    #pragma unroll
    for (int off = 32; off; off >>= 1) m = fmaxf(m, __shfl_xor(m, off, 64));
    v.x = __builtin_amdgcn_exp2f((v.x - m) * LOG2E);
    v.y = __builtin_amdgcn_exp2f((v.y - m) * LOG2E);
    v.z = __builtin_amdgcn_exp2f((v.z - m) * LOG2E);
    v.w = __builtin_amdgcn_exp2f((v.w - m) * LOG2E);
    float s = v.x + v.y + v.z + v.w;
    #pragma unroll
    for (int off = 32; off; off >>= 1) s += __shfl_xor(s, off, 64);
    const float sc = 1.0f / (s * 27.712812921102035f);  // * sqrt(768)
    v.x *= sc; v.y *= sc; v.z *= sc; v.w *= sc;
    p[lane] = v;
}

extern "C" void kernel_launch(void* const* d_in, const int* in_sizes, int n_in,
                              void* d_out, int out_size, void* d_ws, size_t ws_size,
                              hipStream_t stream)
{
    (void)in_sizes; (void)n_in; (void)out_size; (void)ws_size;
    const float* x      = (const float*)d_in[0];
    const float* Wqkv   = (const float*)d_in[1];
    const float* bqkv   = (const float*)d_in[2];
    const float* Wproj  = (const float*)d_in[3];
    const float* bproj  = (const float*)d_in[4];
    const float* mean   = (const float*)d_in[5];
    const float* logvar = (const float*)d_in[6];
    const float* mixc   = (const float*)d_in[7];
    float* out = (float*)d_out;
    float* ws = (float*)d_ws;
    float* qc     = ws + QC_OFF;
    float* keysT  = ws + KT_OFF;
    float* vc     = ws + VC_OFF;
    float* P      = ws + P_OFF;
    float* kmT    = ws + KM_OFF;
    float* energy = ws + EN_OFF;
    float* oat    = ws + OA_OFF;

    // 1a) qkv partials: x @ Wqkv, K split in 2 (2304 waves)
    gemm_k<32><<<dim3(16,36,2),128,0,stream>>>(
        x,768,0,0, Wqkv,2304,0,0, P,2304,0,0,PSTRIDE,
        nullptr, 384, 1, 2);
    // 1b) reduce + bias + scatter to q / keysT / v
    k_qkvreduce<<<1152,256,0,stream>>>(P, bqkv, qc, keysT, vc);
    // 2) key_mix (transposed output kmT[i][row])
    k_mixture<<<1536,256,0,stream>>>(mean, logvar, mixc, keysT, kmT);
    // 3) energy[b,h,q,k] = sum_d q[.,d] * kmT[d][k]  (3072 waves)
    gemm_k<16><<<dim3(16,4,24),128,0,stream>>>(
        qc,768,196608,64, kmT,512,256,32768, energy,256,786432,65536,0,
        nullptr, 64, 12, 1);
    // 4) att = softmax(energy)/sqrt(768), in place
    k_softmax<<<1536,256,0,stream>>>(energy);
    // 5) out_attn = att @ v  (768 waves)
    gemm_k<16><<<dim3(16,1,24),128,0,stream>>>(
        energy,256,786432,65536, vc,768,196608,64, oat,768,196608,64,0,
        nullptr, 256, 12, 1);
    // 6) out = out_attn @ Wproj + bproj  (768 waves)
    gemm_k<16><<<dim3(32,12,1),128,0,stream>>>(
        oat,768,0,0, Wproj,768,0,0, out,768,0,0,0, bproj, 768, 1, 1);
}